// Round 5
// baseline (407.044 us; speedup 1.0000x reference)
//
#include <hip/hip_runtime.h>

#define NND   8192
#define DDIM  256
#define NGRP  32
#define NPGC  256
#define ZEROF 1e-8f
#define LSTR  40   // K-loop LDS row stride in u16 (80 B: 16B-aligned, 2-way banks = free)
#define TSTR  72   // epilogue transpose tile stride in u16 (144 B: 16B-aligned)

typedef unsigned short u16;
typedef __attribute__((ext_vector_type(8))) short short8v;
typedef __attribute__((ext_vector_type(4))) float float4v;

__device__ inline u16 f2bf(float x) {
  unsigned u = __float_as_uint(x);
  u += 0x7fffu + ((u >> 16) & 1u);
  return (u16)(u >> 16);
}
__device__ inline float bf2f(u16 h) { return __uint_as_float((unsigned)h << 16); }
__device__ inline void split2(float x, u16& h, u16& l) {
  h = f2bf(x);
  l = f2bf(x - bf2f(h));
}

__device__ inline float wave_sum(float v) {
#pragma unroll
  for (int off = 32; off > 0; off >>= 1) v += __shfl_down(v, off, 64);
  return v;
}

// ---------------- detection (+ S zero) ----------------
__global__ void k_detect(const int* __restrict__ eraw, const unsigned char* __restrict__ mraw,
                         int* __restrict__ flags, float* __restrict__ S) {
  __shared__ int nzE, nzM;
  if (threadIdx.x == 0) { nzE = 0; nzM = 0; }
  __syncthreads();
  if (eraw[2 * threadIdx.x + 1] != 0) atomicAdd(&nzE, 1);
  int i4 = threadIdx.x * 4;
  int c = (mraw[i4 + 1] != 0) + (mraw[i4 + 2] != 0) + (mraw[i4 + 3] != 0);
  if (c) atomicAdd(&nzM, c);
  S[threadIdx.x] = 0.f;
  __syncthreads();
  if (threadIdx.x == 0) { flags[0] = (nzE == 0); flags[1] = (nzM == 0); }
}

// ---------------- fused dtype conversion: 3 edge arrays + 2 masks ----------------
__global__ void k_cvt_all(const int* __restrict__ e0, const int* __restrict__ e1,
                          const int* __restrict__ e2, const unsigned char* __restrict__ m0,
                          const unsigned char* __restrict__ m1, int* __restrict__ eo,
                          float* __restrict__ emf, float* __restrict__ pmf,
                          int E2, const int* __restrict__ flags) {
  int i = blockIdx.x * 256 + threadIdx.x;
  int fE = flags[0], fM = flags[1];
  if (i < E2) {
    eo[i] = fE ? e0[2 * i] : e0[i];
  } else if (i < 2 * E2) {
    int j = i - E2; eo[E2 + j] = fE ? e1[2 * j] : e1[j];
  } else if (i < 3 * E2) {
    int j = i - 2 * E2; eo[2 * E2 + j] = fE ? e2[2 * j] : e2[j];
  } else if (i < 3 * E2 + NND) {
    int j = i - 3 * E2; unsigned char v = fM ? m0[4 * j] : m0[j];
    emf[j] = 1.f - (float)(v != 0);
  } else if (i < 3 * E2 + 2 * NND) {
    int j = i - 3 * E2 - NND; unsigned char v = fM ? m1[4 * j] : m1[j];
    pmf[j] = 1.f - (float)(v != 0);
  }
}

// ---------------- transpose + bf16-split the 8 weight matrices ----------------
__global__ void k_transpose8(const float* __restrict__ W, const float* __restrict__ T,
                             u16* __restrict__ Wth, u16* __restrict__ Wtl) {
  __shared__ float tile[32][33];
  int mat = blockIdx.z;
  const float* src = (mat < 6) ? (W + (size_t)mat * 65536) : (T + (size_t)(mat - 6) * 65536);
  int k0 = blockIdx.y * 32, n0 = blockIdx.x * 32;
  int r = threadIdx.x >> 3, c4 = (threadIdx.x & 7) * 4;
  const float4 v = *(const float4*)&src[(size_t)(k0 + r) * 256 + n0 + c4];
  tile[r][c4 + 0] = v.x; tile[r][c4 + 1] = v.y; tile[r][c4 + 2] = v.z; tile[r][c4 + 3] = v.w;
  __syncthreads();
  float o[4] = {tile[c4 + 0][r], tile[c4 + 1][r], tile[c4 + 2][r], tile[c4 + 3][r]};
  u16 hh[4], ll[4];
#pragma unroll
  for (int q = 0; q < 4; ++q) split2(o[q], hh[q], ll[q]);
  size_t off = (size_t)mat * 65536 + (size_t)(n0 + r) * 256 + k0 + c4;
  *(ushort4*)&Wth[off] = *(ushort4*)hh;
  *(ushort4*)&Wtl[off] = *(ushort4*)ll;
}

// ---------------- generic fp32 -> hi/lo bf16 split (8 elements/thread) ----------------
__global__ void k_split(const float* __restrict__ in, u16* __restrict__ oh,
                        u16* __restrict__ ol) {
  size_t i = ((size_t)blockIdx.x * 256 + threadIdx.x) * 8;
  float4 a = *(const float4*)&in[i];
  float4 b = *(const float4*)&in[i + 4];
  u16 hh[8], ll[8];
  split2(a.x, hh[0], ll[0]); split2(a.y, hh[1], ll[1]);
  split2(a.z, hh[2], ll[2]); split2(a.w, hh[3], ll[3]);
  split2(b.x, hh[4], ll[4]); split2(b.y, hh[5], ll[5]);
  split2(b.z, hh[6], ll[6]); split2(b.w, hh[7], ll[7]);
  *(ushort4*)&oh[i] = *(ushort4*)hh; *(ushort4*)&oh[i + 4] = *(ushort4*)(hh + 4);
  *(ushort4*)&ol[i] = *(ushort4*)ll; *(ushort4*)&ol[i + 4] = *(ushort4*)(ll + 4);
}

// ---------------- node norms + column sums (fused) ----------------
__global__ void k_norms_colsum(const float* __restrict__ x, float* __restrict__ nrm,
                               float* __restrict__ S) {
  __shared__ float inv[64];
  int n0 = blockIdx.x * 64;
  int tid = threadIdx.x, w = tid >> 6, lane = tid & 63;
  for (int it = 0; it < 16; ++it) {
    int nl = it * 4 + w;
    const float4 v = *(const float4*)&x[(size_t)(n0 + nl) * 256 + lane * 4];
    float s = wave_sum(v.x * v.x + v.y * v.y + v.z * v.z + v.w * v.w);
    if (lane == 0) { float nr = sqrtf(s); nrm[n0 + nl] = nr; inv[nl] = 1.f / nr; }
  }
  __syncthreads();
  float s = 0.f;
  for (int i = 0; i < 64; ++i) s += x[(size_t)(n0 + i) * 256 + tid] * inv[i];
  atomicAdd(&S[tid], s);
}

__global__ void k_dinv(const float* __restrict__ x, const float* __restrict__ S,
                       const float* __restrict__ nrm, float* __restrict__ dinv) {
  int node = blockIdx.x * 4 + (threadIdx.x >> 6);
  int lane = threadIdx.x & 63;
  const float4 v = *(const float4*)&x[(size_t)node * 256 + lane * 4];
  const float4 sv = *(const float4*)&S[lane * 4];
  float s = wave_sum(v.x * sv.x + v.y * sv.y + v.z * sv.z + v.w * sv.w);
  if (lane == 0) {
    float rowsum = s / nrm[node];
    dinv[node] = rsqrtf(fabsf(rowsum) + ZEROF);
  }
}

// ---------------- fused edge scatter (all 3 types) ----------------
__global__ void k_edge3(const int* __restrict__ edges, const float* __restrict__ ew0,
                        const float* __restrict__ ew1, const float* __restrict__ ew2,
                        const float* __restrict__ Abuf, float* __restrict__ Mb3,
                        int E_, int useA) {
  int i = blockIdx.x * 256 + threadIdx.x;
  if (i >= 3 * E_) return;
  int t = i / E_;
  int e = i - t * E_;
  const int* ei = edges + (size_t)t * 2 * E_;
  int src = ei[e], dst = ei[E_ + e];
  float w;
  if (useA) w = Abuf[(size_t)src * 256 + (dst & 255)];
  else      w = (t == 0 ? ew0 : (t == 1 ? ew1 : ew2))[e];
  int g = src >> 8;
  atomicAdd(&Mb3[(((size_t)g * 3 + t) << 16) + ((size_t)(dst & 255) << 8) + (src & 255)], w);
}

// ---------------- unified split-bf16 MFMA GEMM ----------------
// C-tile 64 (frag-rows) x 128 (frag-cols), 4 waves of 32x64, 16x16x32 bf16 MFMA,
// split-bf16x3. All operands pre-split u16 hi/lo; K-loop staging is pure copies.
// frag row axis = a-operand rows; frag col axis = b-operand rows (both NT layout).
// MODE 0: XWT[c][node] = (H @ Wcat)^T     a=Hh(node), b=Wth(c), grid(6,128)
// MODE 1: H = relu(b3 + M @ XWcat)        a=XWT(d),  b=Mh(dst), grid(2,4,32), K=768
// MODE 2: A = (x.xT)*dinv_i dinv_j/(nrm_i nrm_j+eps)  a=b=Hh(x), grid(2,4,32)
// MODE 3: A = 0.5 A + 0.5 sigmoid(tmp.HT) a=tmph, b=Hh, grid(2,4,32)
// MODE 4: tmp[node][d] = H @ T            a=Wth(d), b=Hh(node), grid(64,4)
#define LOAD_REGS(tt, kk)                                                                   \
  {                                                                                         \
    int m_ = tid >> 2, kq_ = (tid & 3) * 8;                                                 \
    size_t aoff_;                                                                           \
    if (MODE == 1)                                                                          \
      aoff_ = (size_t)((tt) * 256 + by * 64 + m_) * 8192 + (size_t)(g * 256 + (kk) + kq_);  \
    else if (MODE == 2 || MODE == 3)                                                        \
      aoff_ = (size_t)(g * 256 + by * 64 + m_) * 256 + (kk) + kq_;                          \
    else                                                                                    \
      aoff_ = (size_t)(by * 64 + m_) * 256 + (kk) + kq_;                                    \
    rAh = *(const short8v*)&Ah_g[aoff_];                                                    \
    rAl = *(const short8v*)&Al_g[aoff_];                                                    \
    int n_ = tid & 127, kq2_ = (tid >> 7) * 16;                                             \
    size_t boff_;                                                                           \
    if (MODE == 1)                                                                          \
      boff_ = (((size_t)g * 3 + (tt)) << 16) + (size_t)(col0 + n_) * 256 + (kk) + kq2_;     \
    else if (MODE == 2 || MODE == 3)                                                        \
      boff_ = (size_t)(g * 256 + col0 + n_) * 256 + (kk) + kq2_;                            \
    else                                                                                    \
      boff_ = (size_t)(col0 + n_) * 256 + (kk) + kq2_;                                      \
    rBh0 = *(const short8v*)&Bh_g[boff_]; rBh1 = *(const short8v*)&Bh_g[boff_ + 8];         \
    rBl0 = *(const short8v*)&Bl_g[boff_]; rBl1 = *(const short8v*)&Bl_g[boff_ + 8];         \
  }

template<int MODE>
__global__ __launch_bounds__(256, 2) void k_mfma(
    const u16* __restrict__ Ah_g, const u16* __restrict__ Al_g,
    const u16* __restrict__ Bh_g, const u16* __restrict__ Bl_g,
    float* __restrict__ Cf, u16* __restrict__ Ch, u16* __restrict__ Cl,
    const float* __restrict__ nrm, const float* __restrict__ dinv,
    const float* __restrict__ bias) {
  __shared__ u16 Ahs[64][LSTR], Als[64][LSTR];
  __shared__ u16 Bhs[128][LSTR], Bls[128][LSTR];
  __shared__ u16 Tt[128][TSTR];
  const int tid = threadIdx.x;
  const int g = blockIdx.z, by = blockIdx.y;
  const int col0 = blockIdx.x * 128;
  const int w = tid >> 6, lane = tid & 63;
  const int lm = lane & 15, lq = lane >> 4;
  const int wr = (w >> 1) * 32, wc = (w & 1) * 64;

  float4v acc[2][4];
#pragma unroll
  for (int i = 0; i < 2; ++i)
#pragma unroll
    for (int j = 0; j < 4; ++j) acc[i][j] = (float4v)0.f;

  short8v rAh, rAl, rBh0, rBh1, rBl0, rBl1;
  const int TOTAL = (MODE == 1) ? 24 : 8;

  LOAD_REGS(0, 0);
  for (int step = 0; step < TOTAL; ++step) {
    if (step) __syncthreads();
    {
      int m = tid >> 2, kq = (tid & 3) * 8;
      *(short8v*)&Ahs[m][kq] = rAh;
      *(short8v*)&Als[m][kq] = rAl;
    }
    {
      int n = tid & 127, kq2 = (tid >> 7) * 16;
      *(short8v*)&Bhs[n][kq2] = rBh0; *(short8v*)&Bhs[n][kq2 + 8] = rBh1;
      *(short8v*)&Bls[n][kq2] = rBl0; *(short8v*)&Bls[n][kq2 + 8] = rBl1;
    }
    __syncthreads();
    int nxt = step + 1;
    if (nxt < TOTAL) {
      int tt = nxt >> 3, kk = (nxt & 7) * 32;
      LOAD_REGS(tt, kk);
    }
    short8v ah[2], al[2], bh[4], bl[4];
#pragma unroll
    for (int i = 0; i < 2; ++i) {
      int r = wr + i * 16 + lm;
      ah[i] = *(const short8v*)&Ahs[r][lq * 8];
      al[i] = *(const short8v*)&Als[r][lq * 8];
    }
#pragma unroll
    for (int j = 0; j < 4; ++j) {
      int r = wc + j * 16 + lm;
      bh[j] = *(const short8v*)&Bhs[r][lq * 8];
      bl[j] = *(const short8v*)&Bls[r][lq * 8];
    }
#pragma unroll
    for (int i = 0; i < 2; ++i)
#pragma unroll
      for (int j = 0; j < 4; ++j) {
        acc[i][j] = __builtin_amdgcn_mfma_f32_16x16x32_bf16(ah[i], bh[j], acc[i][j], 0, 0, 0);
        acc[i][j] = __builtin_amdgcn_mfma_f32_16x16x32_bf16(ah[i], bl[j], acc[i][j], 0, 0, 0);
        acc[i][j] = __builtin_amdgcn_mfma_f32_16x16x32_bf16(al[i], bh[j], acc[i][j], 0, 0, 0);
      }
  }

  // ---- epilogues (frag: col=lm offsets, row=lq*4+r offsets) ----
  if (MODE == 2 || MODE == 3) {
#pragma unroll
    for (int i = 0; i < 2; ++i) {
#pragma unroll
      for (int r = 0; r < 4; ++r) {
        int grow = g * 256 + by * 64 + wr + i * 16 + lq * 4 + r;
        float di = 0.f, ni = 0.f;
        if (MODE == 2) { di = dinv[grow]; ni = nrm[grow]; }
#pragma unroll
        for (int j = 0; j < 4; ++j) {
          int gcol = col0 + wc + j * 16 + lm;
          size_t ci = (size_t)grow * 256 + gcol;
          float v = acc[i][j][r];
          if (MODE == 2) {
            int gj = g * 256 + gcol;
            Cf[ci] = v * di * dinv[gj] / (ni * nrm[gj] + ZEROF);
          } else {
            Cf[ci] = 0.5f * Cf[ci] + 0.5f * (1.f / (1.f + expf(-v)));
          }
        }
      }
    }
  } else {
    // LDS-transpose epilogue, coalesced hi/lo u16 stores.
    float bsum[8];
    if (MODE == 1) {
#pragma unroll
      for (int i = 0; i < 2; ++i)
#pragma unroll
        for (int r = 0; r < 4; ++r) {
          int d = by * 64 + wr + i * 16 + lq * 4 + r;
          bsum[i * 4 + r] = bias[d] + bias[256 + d] + bias[512 + d];
        }
    }
    u16 hv[32], lv[32];
#pragma unroll
    for (int i = 0; i < 2; ++i)
#pragma unroll
      for (int j = 0; j < 4; ++j)
#pragma unroll
        for (int r = 0; r < 4; ++r) {
          float v = acc[i][j][r];
          if (MODE == 1) v = fmaxf(v + bsum[i * 4 + r], 0.f);
          split2(v, hv[(i * 4 + r) * 4 + j], lv[(i * 4 + r) * 4 + j]);
        }
    int ebase1, ebase2;
    size_t estride;
    if (MODE == 0)      { ebase1 = col0;           estride = 8192; ebase2 = by * 64; }
    else if (MODE == 1) { ebase1 = g * 256 + col0; estride = 256;  ebase2 = by * 64; }
    else                { ebase1 = col0;           estride = 256;  ebase2 = by * 64; }
#pragma unroll
    for (int ph = 0; ph < 2; ++ph) {
      __syncthreads();
      const u16* sv = ph ? lv : hv;
#pragma unroll
      for (int i = 0; i < 2; ++i)
#pragma unroll
        for (int j = 0; j < 4; ++j)
#pragma unroll
          for (int r = 0; r < 4; ++r)
            Tt[wc + j * 16 + lm][wr + i * 16 + lq * 4 + r] = sv[(i * 4 + r) * 4 + j];
      __syncthreads();
      u16* dst = ph ? Cl : Ch;
      int cc0 = tid >> 3, mm0 = (tid & 7) * 8;
#pragma unroll
      for (int it = 0; it < 4; ++it) {
        int cc = it * 32 + cc0;
        short8v v = *(const short8v*)&Tt[cc][mm0];
        *(short8v*)&dst[(size_t)(ebase1 + cc) * estride + ebase2 + mm0] = v;
      }
    }
  }
}

// ---------------- fused maps (rowmaps + min/max/sum normalize) ----------------
__global__ void k_maps(const float* __restrict__ Abuf, const float* __restrict__ emf,
                       const float* __restrict__ pmf, float* __restrict__ out) {
  __shared__ float sme[256], smp[256], red[256];
  const int g = blockIdx.x, tid = threadIdx.x, w = tid >> 6, lane = tid & 63;
  const int j0 = g * 256 + lane * 4;
  const float4 pmv = *(const float4*)&pmf[j0];
  const float4 emv = *(const float4*)&emf[j0];
  for (int it = 0; it < 64; ++it) {
    int nl = it * 4 + w;
    const float4 a = *(const float4*)&Abuf[((size_t)g * 256 + nl) * 256 + lane * 4];
    float me = a.x * pmv.x + a.y * pmv.y + a.z * pmv.z + a.w * pmv.w;
    float mp = a.x * emv.x + a.y * emv.y + a.z * emv.z + a.w * emv.w;
#pragma unroll
    for (int off = 32; off > 0; off >>= 1) {
      me += __shfl_down(me, off, 64);
      mp += __shfl_down(mp, off, 64);
    }
    if (lane == 0) { sme[nl] = me; smp[nl] = mp; }
  }
  __syncthreads();
  for (int which = 0; which < 2; ++which) {
    float v = which ? smp[tid] : sme[tid];
    red[tid] = v; __syncthreads();
    for (int s = 128; s > 0; s >>= 1) { if (tid < s) red[tid] = fminf(red[tid], red[tid + s]); __syncthreads(); }
    float mn = red[0]; __syncthreads();
    red[tid] = v; __syncthreads();
    for (int s = 128; s > 0; s >>= 1) { if (tid < s) red[tid] = fmaxf(red[tid], red[tid + s]); __syncthreads(); }
    float mx = red[0]; __syncthreads();
    float m = (v - mn) / (mx - mn + ZEROF);
    red[tid] = m; __syncthreads();
    for (int s = 128; s > 0; s >>= 1) { if (tid < s) red[tid] += red[tid + s]; __syncthreads(); }
    float sum = red[0]; __syncthreads();
    out[which * NND + g * 256 + tid] = m / (sum + ZEROF);
  }
}

// ---------------- launch ----------------
extern "C" void kernel_launch(void* const* d_in, const int* in_sizes, int n_in,
                              void* d_out, int out_size, void* d_ws, size_t ws_size,
                              hipStream_t stream) {
  const float* x = (const float*)d_in[0];
  const unsigned char* em_raw = (const unsigned char*)d_in[7];
  const unsigned char* pm_raw = (const unsigned char*)d_in[8];
  const float* W  = (const float*)d_in[9];
  const float* bg = (const float*)d_in[10];
  const float* T  = (const float*)d_in[11];
  float* out = (float*)d_out;
  const int E_ = in_sizes[2];
  const int E2 = 2 * E_;

  float* ws = (float*)d_ws;
  size_t o = 0;
  float* Abuf = ws + o; o += (size_t)NND * 256;            // 8 MB
  float* Mb3  = ws + o; o += (size_t)NGRP * 3 * 65536;     // 25 MB
  u16* Hh   = (u16*)(ws + o); o += (size_t)NND * 256 / 2;
  u16* Hl   = (u16*)(ws + o); o += (size_t)NND * 256 / 2;
  u16* tmph = (u16*)(ws + o); o += (size_t)NND * 256 / 2;
  u16* tmpl = (u16*)(ws + o); o += (size_t)NND * 256 / 2;
  u16* XWTh = (u16*)(ws + o); o += (size_t)768 * NND / 2;
  u16* XWTl = (u16*)(ws + o); o += (size_t)768 * NND / 2;
  u16* Mh   = (u16*)(ws + o); o += (size_t)NGRP * 3 * 65536 / 2;
  u16* Ml   = (u16*)(ws + o); o += (size_t)NGRP * 3 * 65536 / 2;
  u16* Wth  = (u16*)(ws + o); o += (size_t)8 * 65536 / 2;
  u16* Wtl  = (u16*)(ws + o); o += (size_t)8 * 65536 / 2;
  float* nrm  = ws + o; o += NND;
  float* dinv = ws + o; o += NND;
  float* S    = ws + o; o += 256;
  float* emf  = ws + o; o += NND;
  float* pmf  = ws + o; o += NND;
  int* edges  = (int*)(ws + o); o += (size_t)3 * E2;
  int* flags  = (int*)(ws + o); o += 16;

  // prep
  k_detect<<<1, 256, 0, stream>>>((const int*)d_in[1], em_raw, flags, S);
  int cvtTotal = 3 * E2 + 2 * NND;
  k_cvt_all<<<(cvtTotal + 255) / 256, 256, 0, stream>>>(
      (const int*)d_in[1], (const int*)d_in[3], (const int*)d_in[5],
      em_raw, pm_raw, edges, emf, pmf, E2, flags);
  k_transpose8<<<dim3(8, 8, 8), 256, 0, stream>>>(W, T, Wth, Wtl);
  k_split<<<NND * 256 / 8 / 256, 256, 0, stream>>>(x, Hh, Hl);
  k_norms_colsum<<<NND / 64, 256, 0, stream>>>(x, nrm, S);
  k_dinv<<<NND / 4, 256, 0, stream>>>(x, S, nrm, dinv);

  // initial A (diagonal blocks, factored rowsum)
  k_mfma<2><<<dim3(2, 4, NGRP), 256, 0, stream>>>(
      Hh, Hl, Hh, Hl, Abuf, nullptr, nullptr, nrm, dinv, nullptr);

  const float* ew0 = (const float*)d_in[2];
  const float* ew1 = (const float*)d_in[4];
  const float* ew2 = (const float*)d_in[6];
  const size_t Mbytes = (size_t)NGRP * 3 * 65536 * sizeof(float);
  const int MsplitBlocks = NGRP * 3 * 65536 / 8 / 256;

  for (int l = 0; l < 2; ++l) {
    hipMemsetAsync(Mb3, 0, Mbytes, stream);
    k_edge3<<<(3 * E_ + 255) / 256, 256, 0, stream>>>(edges, ew0, ew1, ew2, Abuf, Mb3, E_, l);
    k_split<<<MsplitBlocks, 256, 0, stream>>>(Mb3, Mh, Ml);
    // XWT = (H @ [W0|W1|W2])^T   (b = Wt rows -> frag col = c)
    k_mfma<0><<<dim3(6, 128, 1), 256, 0, stream>>>(
        Hh, Hl, Wth + (size_t)l * 768 * 256, Wtl + (size_t)l * 768 * 256,
        nullptr, XWTh, XWTl, nullptr, nullptr, nullptr);
    // H = relu(bias3 + sum_t M_t @ XW_t)   (a = XWT rows d, b = M rows dst)
    k_mfma<1><<<dim3(2, 4, NGRP), 256, 0, stream>>>(
        XWTh, XWTl, Mh, Ml, nullptr, Hh, Hl, nullptr, nullptr, bg + (size_t)l * 768);
    // tmp = H @ T[l]   (a = Tt rows d, b = H rows node -> tmp[node][d])
    k_mfma<4><<<dim3(64, 4, 1), 256, 0, stream>>>(
        Wth + (size_t)(6 + l) * 65536, Wtl + (size_t)(6 + l) * 65536, Hh, Hl,
        nullptr, tmph, tmpl, nullptr, nullptr, nullptr);
    // A = 0.5 A + 0.5 sigmoid(tmp @ H^T)
    k_mfma<3><<<dim3(2, 4, NGRP), 256, 0, stream>>>(
        tmph, tmpl, Hh, Hl, Abuf, nullptr, nullptr, nullptr, nullptr, nullptr);
  }

  k_maps<<<NGRP, 256, 0, stream>>>(Abuf, emf, pmf, out);
}

// Round 6
// 321.760 us; speedup vs baseline: 1.2651x; 1.2651x over previous
//
#include <hip/hip_runtime.h>

#define NND   8192
#define DDIM  256
#define NGRP  32
#define ZEROF 1e-8f
#define LSTR  40   // K-loop LDS row stride in u16 (80 B: 16B-aligned, 2-way banks free)
#define TSTR  72   // epilogue transpose tile stride in u16 (144 B)
// flat LDS layout (u16 units)
#define OFF_AH 0
#define OFF_AL 2560
#define OFF_BH 5120
#define OFF_BL 10240
#define OFF_TT 15360
#define LDS_U16 24576

typedef unsigned short u16;
typedef __attribute__((ext_vector_type(8))) short short8v;
typedef __attribute__((ext_vector_type(4))) float float4v;

__device__ inline u16 f2bf(float x) {
  unsigned u = __float_as_uint(x);
  u += 0x7fffu + ((u >> 16) & 1u);
  return (u16)(u >> 16);
}
__device__ inline float bf2f(u16 h) { return __uint_as_float((unsigned)h << 16); }
__device__ inline void split2(float x, u16& h, u16& l) {
  h = f2bf(x);
  l = f2bf(x - bf2f(h));
}

__device__ inline float wave_sum(float v) {
#pragma unroll
  for (int off = 32; off > 0; off >>= 1) v += __shfl_down(v, off, 64);
  return v;
}

// ================= unified split-bf16 MFMA GEMM body =================
// C-tile 64 (frag-rows) x 128 (frag-cols), 4 waves of 32x64, 16x16x32 bf16,
// split-bf16x3 (hh + hl + lh).
// MODE 0: XWT[c][node] = (H @ Wcat)^T      a=H(node), b=Wt(c)
// MODE 1: Hout = relu(b3 + M @ XWcat)      a=XWT(d), b=M fp32(dst), K=768
// MODE 2: A = (x.xT)*di*dj/(ni*nj+eps)     a=b=x
// MODE 3: A = 0.5A + 0.5 sigmoid(tmp.HT)   a=tmp, b=H
// MODE 4: tmp[node][d] = H @ T             a=Tt(d), b=H(node)
#define LOAD_REGS(tt, kk)                                                                   \
  {                                                                                         \
    int m_ = tid >> 2, kq_ = (tid & 3) * 8;                                                 \
    size_t aoff_;                                                                           \
    if (MODE == 1)                                                                          \
      aoff_ = (size_t)((tt) * 256 + bym * 64 + m_) * 8192 + (size_t)(g * 256 + (kk) + kq_); \
    else if (MODE == 2 || MODE == 3)                                                        \
      aoff_ = (size_t)(g * 256 + bym * 64 + m_) * 256 + (kk) + kq_;                         \
    else                                                                                    \
      aoff_ = (size_t)(bym * 64 + m_) * 256 + (kk) + kq_;                                   \
    rAh = *(const short8v*)&Ah_g[aoff_];                                                    \
    rAl = *(const short8v*)&Al_g[aoff_];                                                    \
    if (MODE == 1) {                                                                        \
      int n_ = tid >> 1, kq2_ = (tid & 1) * 16;                                             \
      const float* pb_ = Bfp + (((size_t)g * 3 + (tt)) << 16) +                             \
                         (size_t)(col0 + n_) * 256 + (kk) + kq2_;                           \
      rBf[0] = *(const float4*)pb_;       rBf[1] = *(const float4*)(pb_ + 4);               \
      rBf[2] = *(const float4*)(pb_ + 8); rBf[3] = *(const float4*)(pb_ + 12);              \
    } else {                                                                                \
      int n_ = tid & 127, kq2_ = (tid >> 7) * 16;                                           \
      size_t boff_ = (size_t)(((MODE == 2 || MODE == 3) ? g * 256 : 0) + col0 + n_) * 256   \
                     + (kk) + kq2_;                                                         \
      rBh0 = *(const short8v*)&Bh_g[boff_]; rBh1 = *(const short8v*)&Bh_g[boff_ + 8];       \
      rBl0 = *(const short8v*)&Bl_g[boff_]; rBl1 = *(const short8v*)&Bl_g[boff_ + 8];       \
    }                                                                                       \
  }

template<int MODE>
__device__ __forceinline__ void mfma_body(
    u16* lds,
    const u16* __restrict__ Ah_g, const u16* __restrict__ Al_g,
    const u16* __restrict__ Bh_g, const u16* __restrict__ Bl_g,
    const float* __restrict__ Bfp,
    float* __restrict__ Cf, u16* __restrict__ Ch, u16* __restrict__ Cl,
    const float* __restrict__ nrm, const float* __restrict__ dinv,
    const float* __restrict__ bias,
    int bxm, int bym, int g) {
  u16* Ahs = lds + OFF_AH;   // [64][LSTR]
  u16* Als = lds + OFF_AL;
  u16* Bhs = lds + OFF_BH;   // [128][LSTR]
  u16* Bls = lds + OFF_BL;
  u16* Tt  = lds + OFF_TT;   // [128][TSTR]
  const int tid = threadIdx.x;
  const int col0 = bxm * 128;
  const int w = tid >> 6, lane = tid & 63;
  const int lm = lane & 15, lq = lane >> 4;
  const int wr = (w >> 1) * 32, wc = (w & 1) * 64;

  float4v acc[2][4];
#pragma unroll
  for (int i = 0; i < 2; ++i)
#pragma unroll
    for (int j = 0; j < 4; ++j) acc[i][j] = (float4v)0.f;

  short8v rAh, rAl, rBh0, rBh1, rBl0, rBl1;
  float4 rBf[4];
  const int TOTAL = (MODE == 1) ? 24 : 8;

  LOAD_REGS(0, 0);
  for (int step = 0; step < TOTAL; ++step) {
    if (step) __syncthreads();
    {
      int m = tid >> 2, kq = (tid & 3) * 8;
      *(short8v*)&Ahs[m * LSTR + kq] = rAh;
      *(short8v*)&Als[m * LSTR + kq] = rAl;
    }
    if (MODE == 1) {
      int n = tid >> 1, kq2 = (tid & 1) * 16;
      u16 hh[16], ll[16];
#pragma unroll
      for (int q = 0; q < 4; ++q) {
        split2(rBf[q].x, hh[q * 4 + 0], ll[q * 4 + 0]);
        split2(rBf[q].y, hh[q * 4 + 1], ll[q * 4 + 1]);
        split2(rBf[q].z, hh[q * 4 + 2], ll[q * 4 + 2]);
        split2(rBf[q].w, hh[q * 4 + 3], ll[q * 4 + 3]);
      }
      *(short8v*)&Bhs[n * LSTR + kq2] = *(short8v*)hh;
      *(short8v*)&Bhs[n * LSTR + kq2 + 8] = *(short8v*)(hh + 8);
      *(short8v*)&Bls[n * LSTR + kq2] = *(short8v*)ll;
      *(short8v*)&Bls[n * LSTR + kq2 + 8] = *(short8v*)(ll + 8);
    } else {
      int n = tid & 127, kq2 = (tid >> 7) * 16;
      *(short8v*)&Bhs[n * LSTR + kq2] = rBh0; *(short8v*)&Bhs[n * LSTR + kq2 + 8] = rBh1;
      *(short8v*)&Bls[n * LSTR + kq2] = rBl0; *(short8v*)&Bls[n * LSTR + kq2 + 8] = rBl1;
    }
    __syncthreads();
    int nxt = step + 1;
    if (nxt < TOTAL) {
      int tt = nxt >> 3, kk = (nxt & 7) * 32;
      LOAD_REGS(tt, kk);
    }
    short8v ah[2], al[2], bh[4], bl[4];
#pragma unroll
    for (int i = 0; i < 2; ++i) {
      int r = wr + i * 16 + lm;
      ah[i] = *(const short8v*)&Ahs[r * LSTR + lq * 8];
      al[i] = *(const short8v*)&Als[r * LSTR + lq * 8];
    }
#pragma unroll
    for (int j = 0; j < 4; ++j) {
      int r = wc + j * 16 + lm;
      bh[j] = *(const short8v*)&Bhs[r * LSTR + lq * 8];
      bl[j] = *(const short8v*)&Bls[r * LSTR + lq * 8];
    }
#pragma unroll
    for (int i = 0; i < 2; ++i)
#pragma unroll
      for (int j = 0; j < 4; ++j) {
        acc[i][j] = __builtin_amdgcn_mfma_f32_16x16x32_bf16(ah[i], bh[j], acc[i][j], 0, 0, 0);
        acc[i][j] = __builtin_amdgcn_mfma_f32_16x16x32_bf16(ah[i], bl[j], acc[i][j], 0, 0, 0);
        acc[i][j] = __builtin_amdgcn_mfma_f32_16x16x32_bf16(al[i], bh[j], acc[i][j], 0, 0, 0);
      }
  }

  // ---- epilogues (frag: col=lm, row=lq*4+r) ----
  if (MODE == 2 || MODE == 3) {
#pragma unroll
    for (int i = 0; i < 2; ++i) {
#pragma unroll
      for (int r = 0; r < 4; ++r) {
        int grow = g * 256 + bym * 64 + wr + i * 16 + lq * 4 + r;
        float di = 0.f, ni = 0.f;
        if (MODE == 2) { di = dinv[grow]; ni = nrm[grow]; }
#pragma unroll
        for (int j = 0; j < 4; ++j) {
          int gcol = col0 + wc + j * 16 + lm;
          size_t ci = (size_t)grow * 256 + gcol;
          float v = acc[i][j][r];
          if (MODE == 2) {
            int gj = g * 256 + gcol;
            Cf[ci] = v * di * dinv[gj] / (ni * nrm[gj] + ZEROF);
          } else {
            Cf[ci] = 0.5f * Cf[ci] + 0.5f * (1.f / (1.f + expf(-v)));
          }
        }
      }
    }
  } else {
    // LDS-transpose epilogue, coalesced hi/lo u16 stores.
    float bsum[8];
    if (MODE == 1) {
#pragma unroll
      for (int i = 0; i < 2; ++i)
#pragma unroll
        for (int r = 0; r < 4; ++r) {
          int d = bym * 64 + wr + i * 16 + lq * 4 + r;
          bsum[i * 4 + r] = bias[d] + bias[256 + d] + bias[512 + d];
        }
    }
    u16 hv[32], lv[32];
#pragma unroll
    for (int i = 0; i < 2; ++i)
#pragma unroll
      for (int j = 0; j < 4; ++j)
#pragma unroll
        for (int r = 0; r < 4; ++r) {
          float v = acc[i][j][r];
          if (MODE == 1) v = fmaxf(v + bsum[i * 4 + r], 0.f);
          split2(v, hv[(i * 4 + r) * 4 + j], lv[(i * 4 + r) * 4 + j]);
        }
    int ebase1 = (MODE == 1) ? (g * 256 + col0) : col0;
    int ebase2 = bym * 64;
    size_t estride = (MODE == 0) ? 8192 : 256;
#pragma unroll
    for (int ph = 0; ph < 2; ++ph) {
      __syncthreads();
      const u16* sv = ph ? lv : hv;
#pragma unroll
      for (int i = 0; i < 2; ++i)
#pragma unroll
        for (int j = 0; j < 4; ++j)
#pragma unroll
          for (int r = 0; r < 4; ++r)
            Tt[(wc + j * 16 + lm) * TSTR + wr + i * 16 + lq * 4 + r] = sv[(i * 4 + r) * 4 + j];
      __syncthreads();
      u16* dst = ph ? Cl : Ch;
      int cc0 = tid >> 3, mm0 = (tid & 7) * 8;
#pragma unroll
      for (int it = 0; it < 4; ++it) {
        int cc = it * 32 + cc0;
        short8v v = *(const short8v*)&Tt[cc * TSTR + mm0];
        *(short8v*)&dst[(size_t)(ebase1 + cc) * estride + ebase2 + mm0] = v;
      }
    }
  }
}

// ================= prep: cvt(+flags) | transpose/split W | zero M,S =================
__global__ void k_prep(const int* __restrict__ e0, const int* __restrict__ e1,
                       const int* __restrict__ e2, const unsigned char* __restrict__ m0,
                       const unsigned char* __restrict__ m1,
                       const float* __restrict__ W, const float* __restrict__ T,
                       int* __restrict__ eo, float* __restrict__ emf, float* __restrict__ pmf,
                       u16* __restrict__ Wth, u16* __restrict__ Wtl,
                       float* __restrict__ Mzero, float* __restrict__ S,
                       int E2, int nCvt) {
  __shared__ float tile[32][33];
  __shared__ int nz[2];
  const int b = blockIdx.x, tid = threadIdx.x;
  if (b < nCvt) {
    if (tid < 2) nz[tid] = 0;
    __syncthreads();
    if (e0[2 * tid + 1] != 0) atomicAdd(&nz[0], 1);
    int i4 = tid * 4;
    int c = (m0[i4 + 1] != 0) + (m0[i4 + 2] != 0) + (m0[i4 + 3] != 0);
    if (c) atomicAdd(&nz[1], c);
    __syncthreads();
    int fE = (nz[0] == 0), fM = (nz[1] == 0);
    int i = b * 256 + tid;
    if (i < E2) {
      eo[i] = fE ? e0[2 * i] : e0[i];
    } else if (i < 2 * E2) {
      int j = i - E2; eo[E2 + j] = fE ? e1[2 * j] : e1[j];
    } else if (i < 3 * E2) {
      int j = i - 2 * E2; eo[2 * E2 + j] = fE ? e2[2 * j] : e2[j];
    } else if (i < 3 * E2 + NND) {
      int j = i - 3 * E2; unsigned char v = fM ? m0[4 * j] : m0[j];
      emf[j] = 1.f - (float)(v != 0);
    } else if (i < 3 * E2 + 2 * NND) {
      int j = i - 3 * E2 - NND; unsigned char v = fM ? m1[4 * j] : m1[j];
      pmf[j] = 1.f - (float)(v != 0);
    }
  } else if (b < nCvt + 512) {
    int bb = b - nCvt;
    int mat = bb >> 6, rem = bb & 63;
    int k0 = (rem >> 3) * 32, n0 = (rem & 7) * 32;
    const float* src = (mat < 6) ? (W + (size_t)mat * 65536) : (T + (size_t)(mat - 6) * 65536);
    int r = tid >> 3, c4 = (tid & 7) * 4;
    const float4 v = *(const float4*)&src[(size_t)(k0 + r) * 256 + n0 + c4];
    tile[r][c4 + 0] = v.x; tile[r][c4 + 1] = v.y; tile[r][c4 + 2] = v.z; tile[r][c4 + 3] = v.w;
    __syncthreads();
    float o[4] = {tile[c4 + 0][r], tile[c4 + 1][r], tile[c4 + 2][r], tile[c4 + 3][r]};
    u16 hh[4], ll[4];
#pragma unroll
    for (int q = 0; q < 4; ++q) split2(o[q], hh[q], ll[q]);
    size_t off = (size_t)mat * 65536 + (size_t)(n0 + r) * 256 + k0 + c4;
    *(ushort4*)&Wth[off] = *(ushort4*)hh;
    *(ushort4*)&Wtl[off] = *(ushort4*)ll;
  } else {
    int bb = b - nCvt - 512;           // 0..3072
    if (bb < 3072) {
      float4* p = (float4*)Mzero;
      size_t base = (size_t)bb * 1024 + tid;
      float4 z = make_float4(0.f, 0.f, 0.f, 0.f);
      p[base] = z; p[base + 256] = z; p[base + 512] = z; p[base + 768] = z;
    } else {
      S[tid] = 0.f;
    }
  }
}

// ============ norms + colsums + x split ============
__global__ void k_norms_split(const float* __restrict__ x, float* __restrict__ nrm,
                              float* __restrict__ S, u16* __restrict__ Hh,
                              u16* __restrict__ Hl) {
  __shared__ float inv[64];
  int n0 = blockIdx.x * 64;
  int tid = threadIdx.x, w = tid >> 6, lane = tid & 63;
  for (int it = 0; it < 16; ++it) {
    int nl = it * 4 + w;
    int node = n0 + nl;
    const float4 v = *(const float4*)&x[(size_t)node * 256 + lane * 4];
    u16 hh[4], ll[4];
    split2(v.x, hh[0], ll[0]); split2(v.y, hh[1], ll[1]);
    split2(v.z, hh[2], ll[2]); split2(v.w, hh[3], ll[3]);
    *(ushort4*)&Hh[(size_t)node * 256 + lane * 4] = *(ushort4*)hh;
    *(ushort4*)&Hl[(size_t)node * 256 + lane * 4] = *(ushort4*)ll;
    float s = wave_sum(v.x * v.x + v.y * v.y + v.z * v.z + v.w * v.w);
    if (lane == 0) { float nr = sqrtf(s); nrm[node] = nr; inv[nl] = 1.f / nr; }
  }
  __syncthreads();
  float s = 0.f;
  for (int i = 0; i < 64; ++i) s += x[(size_t)(n0 + i) * 256 + tid] * inv[i];
  atomicAdd(&S[tid], s);
}

// ============ stage A: mode0 GEMM | edge scatter | (l0) dinv ============
__global__ __launch_bounds__(256, 2) void k_stageA(
    const u16* __restrict__ Hinh, const u16* __restrict__ Hinl,
    const u16* __restrict__ Wth, const u16* __restrict__ Wtl, int l,
    u16* __restrict__ XWTh, u16* __restrict__ XWTl,
    const int* __restrict__ edges, const float* __restrict__ ew0,
    const float* __restrict__ ew1, const float* __restrict__ ew2,
    const float* __restrict__ Abuf, float* __restrict__ Mb, int E_,
    const float* __restrict__ x, const float* __restrict__ S,
    const float* __restrict__ nrm, float* __restrict__ dinv) {
  __shared__ u16 lds[LDS_U16];
  const int b = blockIdx.x;
  if (b < 768) {
    mfma_body<0>(lds, Hinh, Hinl, Wth + (size_t)l * 768 * 256, Wtl + (size_t)l * 768 * 256,
                 nullptr, nullptr, XWTh, XWTl, nullptr, nullptr, nullptr,
                 b % 6, b / 6, 0);
  } else if (b < 1024) {
    int bi = b - 768;
    for (int i = bi * 256 + threadIdx.x; i < 3 * E_; i += 65536) {
      int t = i / E_;
      int e = i - t * E_;
      const int* ei = edges + (size_t)t * 2 * E_;
      int src = ei[e], dst = ei[E_ + e];
      float wgt = l ? Abuf[(size_t)src * 256 + (dst & 255)]
                    : (t == 0 ? ew0 : (t == 1 ? ew1 : ew2))[e];
      int gg = src >> 8;
      atomicAdd(&Mb[(((size_t)gg * 3 + t) << 16) + ((size_t)(dst & 255) << 8) + (src & 255)],
                wgt);
    }
  } else {
    int node = (b - 1024) * 4 + (threadIdx.x >> 6);
    int lane = threadIdx.x & 63;
    const float4 v = *(const float4*)&x[(size_t)node * 256 + lane * 4];
    const float4 sv = *(const float4*)&S[lane * 4];
    float s = wave_sum(v.x * sv.x + v.y * sv.y + v.z * sv.z + v.w * sv.w);
    if (lane == 0) {
      float rowsum = s / nrm[node];
      dinv[node] = rsqrtf(fabsf(rowsum) + ZEROF);
    }
  }
}

// ============ stage B: mode1 GEMM | (l0) mode2 init-A GEMM ============
__global__ __launch_bounds__(256, 2) void k_stageB(
    const u16* __restrict__ XWTh, const u16* __restrict__ XWTl,
    const float* __restrict__ Mb,
    u16* __restrict__ Houth, u16* __restrict__ Houtl, const float* __restrict__ bias,
    const u16* __restrict__ xh, const u16* __restrict__ xl, float* __restrict__ Abuf,
    const float* __restrict__ nrm, const float* __restrict__ dinv) {
  __shared__ u16 lds[LDS_U16];
  const int b = blockIdx.x;
  if (b < 256) {
    int g = b & 31, r = b >> 5;
    mfma_body<1>(lds, XWTh, XWTl, nullptr, nullptr, Mb,
                 nullptr, Houth, Houtl, nullptr, nullptr, bias, r & 1, r >> 1, g);
  } else {
    int bb = b - 256;
    int g = bb & 31, r = bb >> 5;
    mfma_body<2>(lds, xh, xl, xh, xl, nullptr, Abuf, nullptr, nullptr,
                 nrm, dinv, nullptr, r & 1, r >> 1, g);
  }
}

// ============ stage C: mode4 (tmp = H @ T) ============
__global__ __launch_bounds__(256, 2) void k_stageC(
    const u16* __restrict__ Wth, const u16* __restrict__ Wtl, int l,
    const u16* __restrict__ Hh, const u16* __restrict__ Hl,
    u16* __restrict__ tmph, u16* __restrict__ tmpl) {
  __shared__ u16 lds[LDS_U16];
  const int b = blockIdx.x;
  mfma_body<4>(lds, Wth + (size_t)(6 + l) * 65536, Wtl + (size_t)(6 + l) * 65536,
               Hh, Hl, nullptr, nullptr, tmph, tmpl, nullptr, nullptr, nullptr,
               b & 63, b >> 6, 0);
}

// ============ stage D: mode3 (A update) ============
__global__ __launch_bounds__(256, 2) void k_stageD(
    const u16* __restrict__ tmph, const u16* __restrict__ tmpl,
    const u16* __restrict__ Hh, const u16* __restrict__ Hl,
    float* __restrict__ Abuf) {
  __shared__ u16 lds[LDS_U16];
  const int b = blockIdx.x;
  int g = b & 31, r = b >> 5;
  mfma_body<3>(lds, tmph, tmpl, Hh, Hl, nullptr, Abuf, nullptr, nullptr,
               nullptr, nullptr, nullptr, r & 1, r >> 1, g);
}

// ============ fused maps ============
__global__ void k_maps(const float* __restrict__ Abuf, const float* __restrict__ emf,
                       const float* __restrict__ pmf, float* __restrict__ out) {
  __shared__ float sme[256], smp[256], red[256];
  const int g = blockIdx.x, tid = threadIdx.x, w = tid >> 6, lane = tid & 63;
  const int j0 = g * 256 + lane * 4;
  const float4 pmv = *(const float4*)&pmf[j0];
  const float4 emv = *(const float4*)&emf[j0];
  for (int it = 0; it < 64; ++it) {
    int nl = it * 4 + w;
    const float4 a = *(const float4*)&Abuf[((size_t)g * 256 + nl) * 256 + lane * 4];
    float me = a.x * pmv.x + a.y * pmv.y + a.z * pmv.z + a.w * pmv.w;
    float mp = a.x * emv.x + a.y * emv.y + a.z * emv.z + a.w * emv.w;
#pragma unroll
    for (int off = 32; off > 0; off >>= 1) {
      me += __shfl_down(me, off, 64);
      mp += __shfl_down(mp, off, 64);
    }
    if (lane == 0) { sme[nl] = me; smp[nl] = mp; }
  }
  __syncthreads();
  for (int which = 0; which < 2; ++which) {
    float v = which ? smp[tid] : sme[tid];
    red[tid] = v; __syncthreads();
    for (int s = 128; s > 0; s >>= 1) { if (tid < s) red[tid] = fminf(red[tid], red[tid + s]); __syncthreads(); }
    float mn = red[0]; __syncthreads();
    red[tid] = v; __syncthreads();
    for (int s = 128; s > 0; s >>= 1) { if (tid < s) red[tid] = fmaxf(red[tid], red[tid + s]); __syncthreads(); }
    float mx = red[0]; __syncthreads();
    float m = (v - mn) / (mx - mn + ZEROF);
    red[tid] = m; __syncthreads();
    for (int s = 128; s > 0; s >>= 1) { if (tid < s) red[tid] += red[tid + s]; __syncthreads(); }
    float sum = red[0]; __syncthreads();
    out[which * NND + g * 256 + tid] = m / (sum + ZEROF);
  }
}

// ================= launch =================
extern "C" void kernel_launch(void* const* d_in, const int* in_sizes, int n_in,
                              void* d_out, int out_size, void* d_ws, size_t ws_size,
                              hipStream_t stream) {
  const float* x = (const float*)d_in[0];
  const unsigned char* em_raw = (const unsigned char*)d_in[7];
  const unsigned char* pm_raw = (const unsigned char*)d_in[8];
  const float* W  = (const float*)d_in[9];
  const float* bg = (const float*)d_in[10];
  const float* T  = (const float*)d_in[11];
  float* out = (float*)d_out;
  const int E_ = in_sizes[2];
  const int E2 = 2 * E_;

  float* ws = (float*)d_ws;
  size_t o = 0;
  float* Abuf = ws + o; o += (size_t)NND * 256;                  // 8 MB
  float* Mb3  = ws + o; o += (size_t)2 * NGRP * 3 * 65536;       // 2 layers x 25 MB
  u16* Hh   = (u16*)(ws + o); o += (size_t)NND * 256 / 2;
  u16* Hl   = (u16*)(ws + o); o += (size_t)NND * 256 / 2;
  u16* H2h  = (u16*)(ws + o); o += (size_t)NND * 256 / 2;
  u16* H2l  = (u16*)(ws + o); o += (size_t)NND * 256 / 2;
  u16* tmph = (u16*)(ws + o); o += (size_t)NND * 256 / 2;
  u16* tmpl = (u16*)(ws + o); o += (size_t)NND * 256 / 2;
  u16* XWTh = (u16*)(ws + o); o += (size_t)768 * NND / 2;
  u16* XWTl = (u16*)(ws + o); o += (size_t)768 * NND / 2;
  u16* Wth  = (u16*)(ws + o); o += (size_t)8 * 65536 / 2;
  u16* Wtl  = (u16*)(ws + o); o += (size_t)8 * 65536 / 2;
  float* nrm  = ws + o; o += NND;
  float* dinv = ws + o; o += NND;
  float* S    = ws + o; o += 256;
  float* emf  = ws + o; o += NND;
  float* pmf  = ws + o; o += NND;
  int* edges  = (int*)(ws + o); o += (size_t)3 * E2;

  const float* ew0 = (const float*)d_in[2];
  const float* ew1 = (const float*)d_in[4];
  const float* ew2 = (const float*)d_in[6];
  float* Mb_l0 = Mb3;
  float* Mb_l1 = Mb3 + (size_t)NGRP * 3 * 65536;

  const int nCvt = (3 * E2 + 2 * NND + 255) / 256;   // 3136 for E=131072

  // 1: cvt+flags | W transpose/split | zero both M buffers + S
  k_prep<<<nCvt + 512 + 3073, 256, 0, stream>>>(
      (const int*)d_in[1], (const int*)d_in[3], (const int*)d_in[5], em_raw, pm_raw,
      W, T, edges, emf, pmf, Wth, Wtl, Mb3, S, E2, nCvt);
  // 2: norms + colsums + x split
  k_norms_split<<<128, 256, 0, stream>>>(x, nrm, S, Hh, Hl);

  // ---- layer 0 ----
  k_stageA<<<3072, 256, 0, stream>>>(Hh, Hl, Wth, Wtl, 0, XWTh, XWTl,
                                     edges, ew0, ew1, ew2, Abuf, Mb_l0, E_,
                                     x, S, nrm, dinv);
  k_stageB<<<512, 256, 0, stream>>>(XWTh, XWTl, Mb_l0, H2h, H2l, bg,
                                    Hh, Hl, Abuf, nrm, dinv);
  k_stageC<<<256, 256, 0, stream>>>(Wth, Wtl, 0, H2h, H2l, tmph, tmpl);
  k_stageD<<<256, 256, 0, stream>>>(tmph, tmpl, H2h, H2l, Abuf);

  // ---- layer 1 ----
  k_stageA<<<1024, 256, 0, stream>>>(H2h, H2l, Wth, Wtl, 1, XWTh, XWTl,
                                     edges, ew0, ew1, ew2, Abuf, Mb_l1, E_,
                                     x, S, nrm, dinv);
  k_stageB<<<256, 256, 0, stream>>>(XWTh, XWTl, Mb_l1, Hh, Hl, bg + 768,
                                    nullptr, nullptr, nullptr, nullptr, nullptr);
  k_stageC<<<256, 256, 0, stream>>>(Wth, Wtl, 1, Hh, Hl, tmph, tmpl);
  k_stageD<<<256, 256, 0, stream>>>(tmph, tmpl, Hh, Hl, Abuf);

  k_maps<<<NGRP, 256, 0, stream>>>(Abuf, emf, pmf, out);
}